// Round 1
// baseline (6299.987 us; speedup 1.0000x reference)
//
#include <hip/hip_runtime.h>
#include <hip/hip_bf16.h>
#include <math.h>

// Problem constants (reference: B=4,S=2048,DM=2048,DC=512,L=4,NS=5)
#define NTOK 8192   // B*S
#define DMD  2048   // d_model
#define DCC  512    // d_cortical

// ---------------- GEMM: C[N,M] = A[N,K] @ W[M,K]^T + bias (+addsrc)(+gelu) --
#define BM 64
#define BN 64
#define BK 32

__global__ __launch_bounds__(256)
void gemm_kernel(const float* __restrict__ A, int lda,
                 const float* __restrict__ W, int ldw,
                 const float* __restrict__ bias,
                 const float* __restrict__ addsrc, int ldadd,
                 float* __restrict__ C, int ldc,
                 int K, int apply_gelu)
{
    // +4 pad keeps float4 alignment (68*4B = 272B, 16B-aligned rows) and
    // breaks the worst write bank conflicts.
    __shared__ __align__(16) float As[BK][BM + 4];
    __shared__ __align__(16) float Ws[BK][BN + 4];

    const int tid = threadIdx.x;
    const int bm = blockIdx.y * BM;   // token tile
    const int bn = blockIdx.x * BN;   // out-feature tile
    const int tx = tid & 15;          // feature dir (4 cols each)
    const int ty = tid >> 4;          // token dir   (4 rows each)

    float acc[4][4] = {};

    for (int k0 = 0; k0 < K; k0 += BK) {
        #pragma unroll
        for (int i = 0; i < 8; ++i) {
            int idx = i * 256 + tid;
            int row = idx >> 5;       // 0..63
            int kk  = idx & 31;       // 0..31
            As[kk][row] = A[(size_t)(bm + row) * lda + k0 + kk];
            Ws[kk][row] = W[(size_t)(bn + row) * ldw + k0 + kk];
        }
        __syncthreads();
        #pragma unroll
        for (int k = 0; k < BK; ++k) {
            float4 av = *(const float4*)&As[k][ty * 4];
            float4 bv = *(const float4*)&Ws[k][tx * 4];
            float a[4] = {av.x, av.y, av.z, av.w};
            float b[4] = {bv.x, bv.y, bv.z, bv.w};
            #pragma unroll
            for (int i = 0; i < 4; ++i)
                #pragma unroll
                for (int j = 0; j < 4; ++j)
                    acc[i][j] = fmaf(a[i], b[j], acc[i][j]);
        }
        __syncthreads();
    }

    #pragma unroll
    for (int i = 0; i < 4; ++i) {
        int r = bm + ty * 4 + i;
        #pragma unroll
        for (int j = 0; j < 4; ++j) {
            int c = bn + tx * 4 + j;
            float v = acc[i][j];
            if (bias)   v += bias[c];
            if (addsrc) v += addsrc[(size_t)r * ldadd + c];
            if (apply_gelu) v = 0.5f * v * (1.0f + erff(v * 0.7071067811865475f));
            C[(size_t)r * ldc + c] = v;
        }
    }
}

// ---------------- LayerNorm helpers (wave per token, DC=512 = 64 lanes x 8) --
__device__ inline float wave_reduce_sum(float v) {
    #pragma unroll
    for (int off = 32; off > 0; off >>= 1) v += __shfl_xor(v, off, 64);
    return v;
}

__device__ inline void load8(const float* p, float* d) {
    float4 u = *(const float4*)p;
    float4 v = *(const float4*)(p + 256);
    d[0]=u.x; d[1]=u.y; d[2]=u.z; d[3]=u.w;
    d[4]=v.x; d[5]=v.y; d[6]=v.z; d[7]=v.w;
}
__device__ inline void store8(float* p, const float* d) {
    *(float4*)p       = make_float4(d[0], d[1], d[2], d[3]);
    *(float4*)(p+256) = make_float4(d[4], d[5], d[6], d[7]);
}

// dst[token,:] = LN(src[token,:]) * g + b
__global__ __launch_bounds__(256)
void ln_kernel(const float* __restrict__ src, const float* __restrict__ g,
               const float* __restrict__ b, float* __restrict__ dst)
{
    const int token = blockIdx.x * 4 + (threadIdx.x >> 6);
    const int lane  = threadIdx.x & 63;
    const size_t base = (size_t)token * DCC;
    const int c0 = lane * 4;

    float x[8];
    load8(src + base + c0, x);
    float s = 0.f, q = 0.f;
    #pragma unroll
    for (int j = 0; j < 8; ++j) { s += x[j]; q += x[j]*x[j]; }
    s = wave_reduce_sum(s); q = wave_reduce_sum(q);
    float m = s * (1.0f / DCC);
    float r = rsqrtf(q * (1.0f / DCC) - m * m + 1e-5f);

    float gg[8], bb[8], o[8];
    load8(g + c0, gg); load8(b + c0, bb);
    #pragma unroll
    for (int j = 0; j < 8; ++j) o[j] = (x[j] - m) * r * gg[j] + bb[j];
    store8(dst + base + c0, o);
}

// compressed = LN(z); t = acts + 0.5*(compressed-target)*sigmoid(logit) + 0.1*lateral;
// out = LN(t).  out may alias acts/target (in-place per token) -> no restrict there.
__global__ __launch_bounds__(256)
void update_ln_kernel(const float* __restrict__ z,
                      const float* acts,
                      const float* target,
                      const float* __restrict__ lateral,
                      const float* __restrict__ logit,
                      const float* __restrict__ g,
                      const float* __restrict__ b,
                      float* outp)
{
    const int token = blockIdx.x * 4 + (threadIdx.x >> 6);
    const int lane  = threadIdx.x & 63;
    const size_t base = (size_t)token * DCC;
    const int c0 = lane * 4;

    // first LN on z
    float zv[8];
    load8(z + base + c0, zv);
    float s = 0.f, q = 0.f;
    #pragma unroll
    for (int j = 0; j < 8; ++j) { s += zv[j]; q += zv[j]*zv[j]; }
    s = wave_reduce_sum(s); q = wave_reduce_sum(q);
    float m1 = s * (1.0f / DCC);
    float r1 = rsqrtf(q * (1.0f / DCC) - m1 * m1 + 1e-5f);

    float gg[8], bb[8];
    load8(g + c0, gg); load8(b + c0, bb);

    float av[8], tv[8], lv[8], pv[8], t[8];
    load8(acts + base + c0, av);
    load8(target + base + c0, tv);
    load8(lateral + base + c0, lv);
    load8(logit + c0, pv);

    float s2 = 0.f, q2 = 0.f;
    #pragma unroll
    for (int j = 0; j < 8; ++j) {
        float comp = (zv[j] - m1) * r1 * gg[j] + bb[j];
        float prec = 1.0f / (1.0f + __expf(-pv[j]));
        float val  = av[j] + 0.5f * (comp - tv[j]) * prec + 0.1f * lv[j];
        t[j] = val;
        s2 += val; q2 += val * val;
    }
    s2 = wave_reduce_sum(s2); q2 = wave_reduce_sum(q2);
    float m2 = s2 * (1.0f / DCC);
    float r2 = rsqrtf(q2 * (1.0f / DCC) - m2 * m2 + 1e-5f);

    float o[8];
    #pragma unroll
    for (int j = 0; j < 8; ++j) o[j] = (t[j] - m2) * r2 * gg[j] + bb[j];
    store8(outp + base + c0, o);
}

// ---------------------------------------------------------------------------
extern "C" void kernel_launch(void* const* d_in, const int* in_sizes, int n_in,
                              void* d_out, int out_size, void* d_ws, size_t ws_size,
                              hipStream_t stream)
{
    const float* qwen   = (const float*)d_in[0];
    const float* obs    = (const float*)d_in[1];
    const float* proj_W = (const float*)d_in[2];
    const float* proj_b = (const float*)d_in[3];
    const float* fuse_W = (const float*)d_in[4];
    const float* fuse_b = (const float*)d_in[5];
    const float* up_W   = (const float*)d_in[6];
    const float* up_b   = (const float*)d_in[7];
    const float* lat_W  = (const float*)d_in[8];
    const float* lat_b  = (const float*)d_in[9];
    const float* plogit = (const float*)d_in[10];
    const float* ln_g   = (const float*)d_in[11];
    const float* ln_b   = (const float*)d_in[12];
    const float* down_W = (const float*)d_in[13];
    const float* down_b = (const float*)d_in[14];
    const float* out1_W = (const float*)d_in[15];
    const float* out1_b = (const float*)d_in[16];
    const float* out2_W = (const float*)d_in[17];
    const float* out2_b = (const float*)d_in[18];
    float* out = (float*)d_out;

    const size_t TOKF = (size_t)NTOK * DCC;   // 4,194,304 floats (16 MB)

    // d_ws layout (100.7 MB): x0, acts[0..3], h
    float* ws = (float*)d_ws;
    float* x0      = ws;
    float* acts[4] = { ws + TOKF, ws + 2*TOKF, ws + 3*TOKF, ws + 4*TOKF };
    float* hbuf    = ws + 5*TOKF;
    // d_out overlay (4 x TOKF = exactly out_size): preds + transient z/lateral.
    // All of d_out is rewritten by the final GEMM.
    float* pred0 = out;
    float* pred1 = out + TOKF;
    float* zbuf  = out + 2*TOKF;
    float* latb  = out + 3*TOKF;

    dim3 blk(256);
    dim3 g512(DCC / BN, NTOK / BM);   // (8, 128)
    dim3 g2048(DMD / BN, NTOK / BM);  // (32, 128)
    dim3 lngrid(NTOK / 4);

    // ---- x0 = fused input: sum over o of (obs_o @ projW_o^T + b) @ fuseW_o^T
    for (int o = 0; o < 4; ++o) {
        gemm_kernel<<<g512, blk, 0, stream>>>(
            obs + (size_t)o * NTOK * DMD, DMD,
            proj_W + (size_t)o * DCC * DMD, DMD,
            proj_b + o * DCC, nullptr, 0,
            zbuf, DCC, DMD, 0);
        gemm_kernel<<<g512, blk, 0, stream>>>(
            zbuf, DCC,
            fuse_W + o * DCC, 4 * DCC,
            (o == 0) ? fuse_b : nullptr,
            (o == 0) ? nullptr : x0, DCC,
            x0, DCC, DCC, 0);
    }

    // ---- initial bottom-up pass
    const float* x = x0;
    for (int i = 0; i < 4; ++i) {
        gemm_kernel<<<g512, blk, 0, stream>>>(
            x, DCC, up_W + (size_t)i * DCC * DCC, DCC,
            up_b + i * DCC, nullptr, 0, zbuf, DCC, DCC, 0);
        ln_kernel<<<lngrid, blk, 0, stream>>>(zbuf, ln_g + i * DCC, ln_b + i * DCC, acts[i]);
        x = acts[i];
    }

    // ---- settling iterations
    for (int s = 0; s < 5; ++s) {
        // top-down predictions from pre-sweep acts (down_W[1], down_W[2] used)
        gemm_kernel<<<g512, blk, 0, stream>>>(
            acts[1], DCC, down_W + (size_t)1 * DCC * DCC, DCC,
            down_b + 1 * DCC, nullptr, 0, pred0, DCC, DCC, 0);
        gemm_kernel<<<g512, blk, 0, stream>>>(
            acts[2], DCC, down_W + (size_t)2 * DCC * DCC, DCC,
            down_b + 2 * DCC, nullptr, 0, pred1, DCC, DCC, 0);

        const float* xin = x0;
        for (int i = 0; i < 4; ++i) {
            gemm_kernel<<<g512, blk, 0, stream>>>(
                xin, DCC, up_W + (size_t)i * DCC * DCC, DCC,
                up_b + i * DCC, nullptr, 0, zbuf, DCC, DCC, 0);
            gemm_kernel<<<g512, blk, 0, stream>>>(
                acts[i], DCC, lat_W + (size_t)i * DCC * DCC, DCC,
                lat_b + i * DCC, nullptr, 0, latb, DCC, DCC, 0);
            const float* tgt = (i == 0) ? pred0 : (i == 1) ? pred1 : acts[i];
            update_ln_kernel<<<lngrid, blk, 0, stream>>>(
                zbuf, acts[i], tgt, latb,
                plogit + i * DCC, ln_g + i * DCC, ln_b + i * DCC, acts[i]);
            xin = acts[i];
        }
    }

    // ---- output head: h = gelu(acts3 @ out1_W^T + b); out = qwen + h @ out2_W^T + b
    gemm_kernel<<<g512, blk, 0, stream>>>(
        acts[3], DCC, out1_W, DCC, out1_b, nullptr, 0, hbuf, DCC, DCC, 1);
    gemm_kernel<<<g2048, blk, 0, stream>>>(
        hbuf, DCC, out2_W, DCC, out2_b, qwen, DMD, out, DMD, DCC, 0);
}

// Round 2
// 1706.434 us; speedup vs baseline: 3.6919x; 3.6919x over previous
//
#include <hip/hip_runtime.h>
#include <hip/hip_bf16.h>
#include <math.h>

#define NTOK 8192   // B*S
#define DMD  2048   // d_model
#define DCC  512    // d_cortical
#define TOKH 4194304  // NTOK*DCC

#define TM 128
#define TN 64
#define BK 32

typedef __attribute__((ext_vector_type(8))) short short8;
typedef __attribute__((ext_vector_type(4))) float f32x4;

// ---------------- helpers ---------------------------------------------------
__device__ inline float bf2f(unsigned short u) {
    union { unsigned int i; float f; } x; x.i = ((unsigned int)u) << 16; return x.f;
}
__device__ inline unsigned short f2bf(float f) {
    union { float f; unsigned int i; } x; x.f = f;
    unsigned int u = x.i;
    return (unsigned short)((u + 0x7fffu + ((u >> 16) & 1u)) >> 16);
}

// async global->LDS, 16B per lane. LDS dest must be wave-uniform base;
// HW scatters lane i to base + i*16.
typedef const __attribute__((address_space(1))) unsigned int* gas1_t;
typedef __attribute__((address_space(3))) unsigned int* las3_t;
__device__ inline void async16(const void* g, void* l) {
    __builtin_amdgcn_global_load_lds(
        (gas1_t)g,
        (las3_t)(unsigned int)(unsigned long long)l, 16, 0, 0);
}

__device__ inline short8 pack8(f32x4 u, f32x4 v) {
    union { short8 s; __hip_bfloat162 h[4]; } r;
    r.h[0] = __float22bfloat162_rn(float2{u.x, u.y});
    r.h[1] = __float22bfloat162_rn(float2{u.z, u.w});
    r.h[2] = __float22bfloat162_rn(float2{v.x, v.y});
    r.h[3] = __float22bfloat162_rn(float2{v.z, v.w});
    return r.s;
}

__device__ inline float wave_reduce_sum(float v) {
    #pragma unroll
    for (int off = 32; off > 0; off >>= 1) v += __shfl_xor(v, off, 64);
    return v;
}

// ---------------- fp32 -> bf16 conversion -----------------------------------
__global__ __launch_bounds__(256)
void cvt_kernel(const float* __restrict__ s, unsigned short* __restrict__ d, int n4)
{
    int i = blockIdx.x * 256 + threadIdx.x;
    if (i >= n4) return;
    float4 v = ((const float4*)s)[i];
    ushort4 o;
    o.x = f2bf(v.x); o.y = f2bf(v.y); o.z = f2bf(v.z); o.w = f2bf(v.w);
    ((ushort4*)d)[i] = o;
}

// ---------------- batched bf16 MFMA GEMM ------------------------------------
// C[M,N] = A[M,K] @ W[N,K]^T + bias (+add) (gelu).  blockIdx.z picks batch slot.
struct GArgs {
    const void*           A[4];
    const unsigned short* W[4];
    const float*          bias[4];
    const float*          add[4];
    void*                 C[4];
};

template<bool AF32, bool OUTF32, bool GELU>
__global__ __launch_bounds__(256, AF32 ? 2 : 4)
void gemm16(GArgs ga, int lda, int ldw, int ldadd, int ldc, int K)
{
    // A-tile: bf16 path 128x32x2B = 8KB (low half); f32 path 128x32x4B = 16KB
    __shared__ float AsStore[TM * BK];           // 16 KB
    __shared__ unsigned short Bs[TN * BK];       // 4 KB
    unsigned short* As = (unsigned short*)AsStore;
    float* Asf = AsStore;

    const int z    = blockIdx.z;
    const int tid  = threadIdx.x;
    const int wave = tid >> 6;
    const int lane = tid & 63;
    const int bm   = blockIdx.y * TM;
    const int bn   = blockIdx.x * TN;
    const int wr   = wave >> 1;   // wave row (0..1) -> 64 rows
    const int wc   = wave & 1;    // wave col (0..1) -> 32 cols

    const unsigned short* Wp  = ga.W[z];
    const unsigned short* A16 = (const unsigned short*)ga.A[z];
    const float*          A32 = (const float*)ga.A[z];

    f32x4 acc[4][2] = {};

    for (int k0 = 0; k0 < K; k0 += BK) {
        // ---- stage B (64x32 bf16 = 4KB): wave w stages rows [w*16, w*16+16)
        {
            int row = wave * 16 + (lane >> 2);
            int kq  = (lane & 3) * 8;
            async16(Wp + (size_t)(bn + row) * ldw + k0 + kq, Bs + wave * 512);
        }
        // ---- stage A
        if (AF32) {
            #pragma unroll
            for (int r = 0; r < 4; ++r) {
                int chunk = wave + r * 4;           // 16 chunks of 1024B
                int row   = chunk * 8 + (lane >> 3);
                int kq    = (lane & 7) * 4;
                async16(A32 + (size_t)(bm + row) * lda + k0 + kq, Asf + chunk * 256);
            }
        } else {
            #pragma unroll
            for (int r = 0; r < 2; ++r) {
                int chunk = wave + r * 4;           // 8 chunks of 1024B
                int row   = chunk * 16 + (lane >> 2);
                int kq    = (lane & 3) * 8;
                async16(A16 + (size_t)(bm + row) * lda + k0 + kq, As + chunk * 512);
            }
        }
        __syncthreads();

        // ---- fragments + MFMA (16x16x32: A[m=lane&15][k=(lane>>4)*8+j])
        short8 bfrag[2];
        #pragma unroll
        for (int ni = 0; ni < 2; ++ni)
            bfrag[ni] = *(const short8*)&Bs[(wc * 32 + ni * 16 + (lane & 15)) * 32 + (lane >> 4) * 8];

        #pragma unroll
        for (int mi = 0; mi < 4; ++mi) {
            int rl = wr * 64 + mi * 16 + (lane & 15);
            short8 afrag;
            if (AF32) {
                const float* p = Asf + rl * 32 + (lane >> 4) * 8;
                f32x4 u = *(const f32x4*)p;
                f32x4 v = *(const f32x4*)(p + 4);
                afrag = pack8(u, v);
            } else {
                afrag = *(const short8*)&As[rl * 32 + (lane >> 4) * 8];
            }
            #pragma unroll
            for (int ni = 0; ni < 2; ++ni)
                acc[mi][ni] = __builtin_amdgcn_mfma_f32_16x16x32_bf16(
                    afrag, bfrag[ni], acc[mi][ni], 0, 0, 0);
        }
        __syncthreads();
    }

    // ---- epilogue: C/D layout col=lane&15, row=(lane>>4)*4+reg
    const float* bias = ga.bias[z];
    const float* add  = ga.add[z];
    #pragma unroll
    for (int ni = 0; ni < 2; ++ni) {
        int col = bn + wc * 32 + ni * 16 + (lane & 15);
        float bv = bias ? bias[col] : 0.0f;
        #pragma unroll
        for (int mi = 0; mi < 4; ++mi) {
            #pragma unroll
            for (int r = 0; r < 4; ++r) {
                int row = bm + wr * 64 + mi * 16 + (lane >> 4) * 4 + r;
                float vv = acc[mi][ni][r] + bv;
                if (GELU) vv = 0.5f * vv * (1.0f + erff(vv * 0.7071067811865475f));
                if (OUTF32) {
                    if (add) vv += add[(size_t)row * ldadd + col];
                    ((float*)ga.C[z])[(size_t)row * ldc + col] = vv;
                } else {
                    ((unsigned short*)ga.C[z])[(size_t)row * ldc + col] = f2bf(vv);
                }
            }
        }
    }
}

// ---------------- LayerNorm (bf16 in/out, fp32 math) ------------------------
__global__ __launch_bounds__(256)
void ln16_kernel(const unsigned short* __restrict__ src, const float* __restrict__ g,
                 const float* __restrict__ b, unsigned short* __restrict__ dst)
{
    const int token = blockIdx.x * 4 + (threadIdx.x >> 6);
    const int lane  = threadIdx.x & 63;
    const size_t base = (size_t)token * DCC + lane * 8;
    const int c0 = lane * 8;

    short8 raw = *(const short8*)(src + base);
    float x[8], s = 0.f, q = 0.f;
    #pragma unroll
    for (int j = 0; j < 8; ++j) {
        x[j] = bf2f((unsigned short)raw[j]);
        s += x[j]; q += x[j] * x[j];
    }
    s = wave_reduce_sum(s); q = wave_reduce_sum(q);
    float m = s * (1.0f / DCC);
    float r = rsqrtf(q * (1.0f / DCC) - m * m + 1e-5f);

    float4 g0 = *(const float4*)(g + c0), g1 = *(const float4*)(g + c0 + 4);
    float4 b0 = *(const float4*)(b + c0), b1 = *(const float4*)(b + c0 + 4);
    float gg[8] = {g0.x,g0.y,g0.z,g0.w,g1.x,g1.y,g1.z,g1.w};
    float bb[8] = {b0.x,b0.y,b0.z,b0.w,b1.x,b1.y,b1.z,b1.w};

    short8 o;
    #pragma unroll
    for (int j = 0; j < 8; ++j)
        o[j] = (short)f2bf((x[j] - m) * r * gg[j] + bb[j]);
    *(short8*)(dst + base) = o;
}

// compressed = LN(z); t = a + 0.5*(compressed-target)*sigmoid(logit) + 0.1*lat;
// out = LN(t). out aliases a (in-place per token).
__global__ __launch_bounds__(256)
void update16_kernel(const unsigned short* __restrict__ z,
                     const unsigned short* a,
                     const unsigned short* t,
                     const unsigned short* __restrict__ lat,
                     const float* __restrict__ logit,
                     const float* __restrict__ g,
                     const float* __restrict__ b,
                     unsigned short* outp)
{
    const int token = blockIdx.x * 4 + (threadIdx.x >> 6);
    const int lane  = threadIdx.x & 63;
    const size_t base = (size_t)token * DCC + lane * 8;
    const int c0 = lane * 8;

    short8 zr = *(const short8*)(z + base);
    float zv[8], s = 0.f, q = 0.f;
    #pragma unroll
    for (int j = 0; j < 8; ++j) {
        zv[j] = bf2f((unsigned short)zr[j]);
        s += zv[j]; q += zv[j] * zv[j];
    }
    s = wave_reduce_sum(s); q = wave_reduce_sum(q);
    float m1 = s * (1.0f / DCC);
    float r1 = rsqrtf(q * (1.0f / DCC) - m1 * m1 + 1e-5f);

    float4 g0 = *(const float4*)(g + c0), g1 = *(const float4*)(g + c0 + 4);
    float4 b0 = *(const float4*)(b + c0), b1 = *(const float4*)(b + c0 + 4);
    float4 p0 = *(const float4*)(logit + c0), p1 = *(const float4*)(logit + c0 + 4);
    float gg[8] = {g0.x,g0.y,g0.z,g0.w,g1.x,g1.y,g1.z,g1.w};
    float bb[8] = {b0.x,b0.y,b0.z,b0.w,b1.x,b1.y,b1.z,b1.w};
    float pv[8] = {p0.x,p0.y,p0.z,p0.w,p1.x,p1.y,p1.z,p1.w};

    short8 ar = *(const short8*)(a + base);
    short8 tr = *(const short8*)(t + base);
    short8 lr = *(const short8*)(lat + base);

    float tv[8], s2 = 0.f, q2 = 0.f;
    #pragma unroll
    for (int j = 0; j < 8; ++j) {
        float comp = (zv[j] - m1) * r1 * gg[j] + bb[j];
        float prec = 1.0f / (1.0f + __expf(-pv[j]));
        float val  = bf2f((unsigned short)ar[j])
                   + 0.5f * (comp - bf2f((unsigned short)tr[j])) * prec
                   + 0.1f * bf2f((unsigned short)lr[j]);
        tv[j] = val;
        s2 += val; q2 += val * val;
    }
    s2 = wave_reduce_sum(s2); q2 = wave_reduce_sum(q2);
    float m2 = s2 * (1.0f / DCC);
    float r2 = rsqrtf(q2 * (1.0f / DCC) - m2 * m2 + 1e-5f);

    short8 o;
    #pragma unroll
    for (int j = 0; j < 8; ++j)
        o[j] = (short)f2bf((tv[j] - m2) * r2 * gg[j] + bb[j]);
    *(short8*)(outp + base) = o;
}

// ---------------------------------------------------------------------------
extern "C" void kernel_launch(void* const* d_in, const int* in_sizes, int n_in,
                              void* d_out, int out_size, void* d_ws, size_t ws_size,
                              hipStream_t stream)
{
    const float* qwen   = (const float*)d_in[0];
    const float* obs    = (const float*)d_in[1];
    const float* proj_W = (const float*)d_in[2];
    const float* proj_b = (const float*)d_in[3];
    const float* fuse_W = (const float*)d_in[4];
    const float* fuse_b = (const float*)d_in[5];
    const float* up_W   = (const float*)d_in[6];
    const float* up_b   = (const float*)d_in[7];
    const float* lat_W  = (const float*)d_in[8];
    const float* lat_b  = (const float*)d_in[9];
    const float* plogit = (const float*)d_in[10];
    const float* ln_g   = (const float*)d_in[11];
    const float* ln_b   = (const float*)d_in[12];
    const float* down_W = (const float*)d_in[13];
    const float* down_b = (const float*)d_in[14];
    const float* out1_W = (const float*)d_in[15];
    const float* out1_b = (const float*)d_in[16];
    const float* out2_W = (const float*)d_in[17];
    const float* out2_b = (const float*)d_in[18];
    float* out = (float*)d_out;

    // ---- ws layout (ushort), total ~69 MB (proven ws_size >= 100.7 MB)
    unsigned short* wsu = (unsigned short*)d_ws;
    unsigned short* x0b      = wsu;                    // TOKH
    unsigned short* acts16[4] = { wsu + TOKH, wsu + 2*TOKH, wsu + 3*TOKH, wsu + 4*TOKH };
    unsigned short* h16      = wsu + 5 * TOKH;
    unsigned short* w16      = wsu + 6 * TOKH;         // weights, 9.44M ushort
    unsigned short* projW16  = w16;                    // 4*512*2048 = 4194304
    unsigned short* fuseW16  = w16 + 4194304;          // 1048576
    unsigned short* upW16    = w16 + 5242880;          // 1048576
    unsigned short* latW16   = w16 + 6291456;          // 1048576
    unsigned short* downW16  = w16 + 7340032;          // 786432
    unsigned short* out1W16  = w16 + 8126464;          // 262144
    unsigned short* out2W16  = w16 + 8388608;          // 1048576

    // ---- d_out overlays (all fully rewritten by the final GEMM)
    unsigned short* outu   = (unsigned short*)d_out;
    unsigned short* catbuf = outu;                     // phase 1: 8192x2048 bf16 (33.5MB)
    unsigned short* pred16a = outu;                    // settle phase
    unsigned short* pred16b = outu + TOKH;
    unsigned short* z16     = outu + 2 * TOKH;
    unsigned short* lat16   = outu + 3 * TOKH;

    dim3 blk(256);
    dim3 lngrid(NTOK / 4);

    // ---- weight conversions (run every launch; ws is re-poisoned)
    auto cvt = [&](const float* s, unsigned short* d, int n) {
        int n4 = n / 4;
        cvt_kernel<<<dim3((n4 + 255) / 256), blk, 0, stream>>>(s, d, n4);
    };
    cvt(proj_W, projW16, 4 * DCC * DMD);
    cvt(fuse_W, fuseW16, DCC * 4 * DCC);
    cvt(up_W,   upW16,   4 * DCC * DCC);
    cvt(lat_W,  latW16,  4 * DCC * DCC);
    cvt(down_W, downW16, 3 * DCC * DCC);
    cvt(out1_W, out1W16, DCC * DCC);
    cvt(out2_W, out2W16, DMD * DCC);

    // ---- proj (batched over 4 observed layers, fp32 A): cat[:, o*512:+512]
    {
        GArgs a{};
        for (int o = 0; o < 4; ++o) {
            a.A[o]    = obs + (size_t)o * NTOK * DMD;
            a.W[o]    = projW16 + (size_t)o * DCC * DMD;
            a.bias[o] = proj_b + o * DCC;
            a.C[o]    = catbuf + o * DCC;        // ldc = 2048, column offset
        }
        gemm16<true, false, false><<<dim3(DCC/TN, NTOK/TM, 4), blk, 0, stream>>>(
            a, DMD, DMD, 0, 4 * DCC, DMD);
    }
    // ---- fuse: x0 = cat @ fuse_W^T + fuse_b  (K=2048)
    {
        GArgs a{};
        a.A[0] = catbuf; a.W[0] = fuseW16; a.bias[0] = fuse_b; a.C[0] = x0b;
        gemm16<false, false, false><<<dim3(DCC/TN, NTOK/TM, 1), blk, 0, stream>>>(
            a, 4 * DCC, 4 * DCC, 0, DCC, 4 * DCC);
    }

    // ---- initial bottom-up pass
    for (int i = 0; i < 4; ++i) {
        GArgs a{};
        a.A[0] = (i == 0) ? x0b : acts16[i - 1];
        a.W[0] = upW16 + (size_t)i * DCC * DCC;
        a.bias[0] = up_b + i * DCC;
        a.C[0] = z16;
        gemm16<false, false, false><<<dim3(DCC/TN, NTOK/TM, 1), blk, 0, stream>>>(
            a, DCC, DCC, 0, DCC, DCC);
        ln16_kernel<<<lngrid, blk, 0, stream>>>(z16, ln_g + i * DCC, ln_b + i * DCC, acts16[i]);
    }

    // ---- settling iterations
    for (int s = 0; s < 5; ++s) {
        // preds from pre-sweep acts: pred0 = acts[1]@down_W[1]^T, pred1 = acts[2]@down_W[2]^T
        {
            GArgs a{};
            a.A[0] = acts16[1]; a.W[0] = downW16 + (size_t)1 * DCC * DCC;
            a.bias[0] = down_b + 1 * DCC; a.C[0] = pred16a;
            a.A[1] = acts16[2]; a.W[1] = downW16 + (size_t)2 * DCC * DCC;
            a.bias[1] = down_b + 2 * DCC; a.C[1] = pred16b;
            gemm16<false, false, false><<<dim3(DCC/TN, NTOK/TM, 2), blk, 0, stream>>>(
                a, DCC, DCC, 0, DCC, DCC);
        }
        for (int i = 0; i < 4; ++i) {
            GArgs a{};
            a.A[0] = (i == 0) ? x0b : acts16[i - 1];
            a.W[0] = upW16 + (size_t)i * DCC * DCC;
            a.bias[0] = up_b + i * DCC;
            a.C[0] = z16;
            a.A[1] = acts16[i];
            a.W[1] = latW16 + (size_t)i * DCC * DCC;
            a.bias[1] = lat_b + i * DCC;
            a.C[1] = lat16;
            gemm16<false, false, false><<<dim3(DCC/TN, NTOK/TM, 2), blk, 0, stream>>>(
                a, DCC, DCC, 0, DCC, DCC);
            const unsigned short* tgt = (i == 0) ? pred16a : (i == 1) ? pred16b : acts16[i];
            update16_kernel<<<lngrid, blk, 0, stream>>>(
                z16, acts16[i], tgt, lat16,
                plogit + i * DCC, ln_g + i * DCC, ln_b + i * DCC, acts16[i]);
        }
    }

    // ---- head
    {
        GArgs a{};
        a.A[0] = acts16[3]; a.W[0] = out1W16; a.bias[0] = out1_b; a.C[0] = h16;
        gemm16<false, false, true><<<dim3(DCC/TN, NTOK/TM, 1), blk, 0, stream>>>(
            a, DCC, DCC, 0, DCC, DCC);
    }
    {
        GArgs a{};
        a.A[0] = h16; a.W[0] = out2W16; a.bias[0] = out2_b;
        a.add[0] = qwen; a.C[0] = out;
        gemm16<false, true, false><<<dim3(DMD/TN, NTOK/TM, 1), blk, 0, stream>>>(
            a, DCC, DCC, DMD, DMD, DCC);
    }
}

// Round 3
// 1621.348 us; speedup vs baseline: 3.8856x; 1.0525x over previous
//
#include <hip/hip_runtime.h>
#include <hip/hip_bf16.h>
#include <math.h>

#define NTOK 8192     // B*S
#define DMD  2048     // d_model
#define DCC  512      // d_cortical
#define TOKH 4194304  // NTOK*DCC

typedef __attribute__((ext_vector_type(8))) short short8;
typedef __attribute__((ext_vector_type(4))) float f32x4;

// ---------------- helpers ---------------------------------------------------
__device__ inline float bf2f(unsigned short u) {
    union { unsigned int i; float f; } x; x.i = ((unsigned int)u) << 16; return x.f;
}
__device__ inline unsigned short f2bf(float f) {
    union { float f; unsigned int i; } x; x.f = f;
    unsigned int u = x.i;
    return (unsigned short)((u + 0x7fffu + ((u >> 16) & 1u)) >> 16);
}

// async global->LDS, 16B per lane; LDS dest is wave-uniform base + lane*16.
typedef const __attribute__((address_space(1))) unsigned int* gas1_t;
typedef __attribute__((address_space(3))) unsigned int* las3_t;
__device__ inline void async16(const void* g, void* l) {
    __builtin_amdgcn_global_load_lds(
        (gas1_t)g,
        (las3_t)(unsigned int)(unsigned long long)l, 16, 0, 0);
}

__device__ inline float wave_reduce_sum(float v) {
    #pragma unroll
    for (int off = 32; off > 0; off >>= 1) v += __shfl_xor(v, off, 64);
    return v;
}

// ---------------- fp32 -> bf16 conversion -----------------------------------
__global__ __launch_bounds__(256)
void cvt_kernel(const float* __restrict__ s, unsigned short* __restrict__ d, int n4)
{
    int i = blockIdx.x * 256 + threadIdx.x;
    if (i >= n4) return;
    float4 v = ((const float4*)s)[i];
    ushort4 o;
    o.x = f2bf(v.x); o.y = f2bf(v.y); o.z = f2bf(v.z); o.w = f2bf(v.w);
    ((ushort4*)d)[i] = o;
}

// ---------------- batched bf16 MFMA GEMM (m97 structure) --------------------
// C[M,N] = A[M,K] @ W[N,K]^T + bias (+add fp32) (gelu). blockIdx.z = batch slot.
// Tile 128x128, 4 waves, each wave 64x64 -> 16 MFMA : 8 ds_read_b128 : 4 glds
// per wave-kstep (the proven m97 density).
struct GArgs {
    const unsigned short* A[6];
    const unsigned short* W[6];
    const float*          bias[6];
    const float*          add[6];
    void*                 C[6];
};

template<bool OUTF32, bool GELU>
__global__ __launch_bounds__(256)
void gemm16(GArgs ga, int lda, int ldw, int ldadd, int ldc, int K)
{
    __shared__ unsigned short As[128 * 32];   // 8 KB
    __shared__ unsigned short Bs[128 * 32];   // 8 KB

    const int z    = blockIdx.z;
    const int tid  = threadIdx.x;
    const int wave = tid >> 6;
    const int lane = tid & 63;
    const int bm   = blockIdx.y * 128;
    const int bn   = blockIdx.x * 128;
    const int wr   = wave >> 1;   // 0..1 -> 64-row half
    const int wc   = wave & 1;    // 0..1 -> 64-col half

    const unsigned short* Ap = ga.A[z];
    const unsigned short* Wp = ga.W[z];

    const int lrow = lane >> 2;         // 0..15
    const int lcol = (lane & 3) * 8;    // 0,8,16,24

    f32x4 acc[4][4] = {};

    for (int k0 = 0; k0 < K; k0 += 32) {
        // stage A and B tiles (each 128x32 bf16 = 8KB = 8 chunks of 1KB)
        #pragma unroll
        for (int r = 0; r < 2; ++r) {
            int c = wave + r * 4;
            async16(Ap + (size_t)(bm + c * 16 + lrow) * lda + k0 + lcol, As + c * 512);
            async16(Wp + (size_t)(bn + c * 16 + lrow) * ldw + k0 + lcol, Bs + c * 512);
        }
        __syncthreads();

        // fragments: A[m=lane&15][k=(lane>>4)*8+j]
        short8 af[4], bfr[4];
        #pragma unroll
        for (int i = 0; i < 4; ++i) {
            af[i]  = *(const short8*)&As[(wr * 64 + i * 16 + (lane & 15)) * 32 + (lane >> 4) * 8];
            bfr[i] = *(const short8*)&Bs[(wc * 64 + i * 16 + (lane & 15)) * 32 + (lane >> 4) * 8];
        }
        #pragma unroll
        for (int mi = 0; mi < 4; ++mi)
            #pragma unroll
            for (int ni = 0; ni < 4; ++ni)
                acc[mi][ni] = __builtin_amdgcn_mfma_f32_16x16x32_bf16(
                    af[mi], bfr[ni], acc[mi][ni], 0, 0, 0);
        __syncthreads();
    }

    // epilogue: C/D layout col=lane&15, row=(lane>>4)*4+reg
    const float* bias = ga.bias[z];
    const float* add  = ga.add[z];
    #pragma unroll
    for (int ni = 0; ni < 4; ++ni) {
        int col = bn + wc * 64 + ni * 16 + (lane & 15);
        float bv = bias ? bias[col] : 0.0f;
        #pragma unroll
        for (int mi = 0; mi < 4; ++mi) {
            #pragma unroll
            for (int r = 0; r < 4; ++r) {
                int row = bm + wr * 64 + mi * 16 + (lane >> 4) * 4 + r;
                float vv = acc[mi][ni][r] + bv;
                if (GELU) vv = 0.5f * vv * (1.0f + erff(vv * 0.7071067811865475f));
                if (OUTF32) {
                    if (add) vv += add[(size_t)row * ldadd + col];
                    ((float*)ga.C[z])[(size_t)row * ldc + col] = vv;
                } else {
                    ((unsigned short*)ga.C[z])[(size_t)row * ldc + col] = f2bf(vv);
                }
            }
        }
    }
}

// ---------------- LayerNorm (bf16 in/out, fp32 math) ------------------------
__global__ __launch_bounds__(256)
void ln16_kernel(const unsigned short* __restrict__ src, const float* __restrict__ g,
                 const float* __restrict__ b, unsigned short* __restrict__ dst)
{
    const int token = blockIdx.x * 4 + (threadIdx.x >> 6);
    const int lane  = threadIdx.x & 63;
    const size_t base = (size_t)token * DCC + lane * 8;
    const int c0 = lane * 8;

    short8 raw = *(const short8*)(src + base);
    float x[8], s = 0.f, q = 0.f;
    #pragma unroll
    for (int j = 0; j < 8; ++j) {
        x[j] = bf2f((unsigned short)raw[j]);
        s += x[j]; q += x[j] * x[j];
    }
    s = wave_reduce_sum(s); q = wave_reduce_sum(q);
    float m = s * (1.0f / DCC);
    float r = rsqrtf(q * (1.0f / DCC) - m * m + 1e-5f);

    float4 g0 = *(const float4*)(g + c0), g1 = *(const float4*)(g + c0 + 4);
    float4 b0 = *(const float4*)(b + c0), b1 = *(const float4*)(b + c0 + 4);
    float gg[8] = {g0.x,g0.y,g0.z,g0.w,g1.x,g1.y,g1.z,g1.w};
    float bb[8] = {b0.x,b0.y,b0.z,b0.w,b1.x,b1.y,b1.z,b1.w};

    short8 o;
    #pragma unroll
    for (int j = 0; j < 8; ++j)
        o[j] = (short)f2bf((x[j] - m) * r * gg[j] + bb[j]);
    *(short8*)(dst + base) = o;
}

// compressed = LN(z); t = a + 0.5*(compressed-target)*sigmoid(logit) + 0.1*lat;
// out = LN(t). out aliases a (in-place per token).
__global__ __launch_bounds__(256)
void update16_kernel(const unsigned short* __restrict__ z,
                     const unsigned short* a,
                     const unsigned short* t,
                     const unsigned short* __restrict__ lat,
                     const float* __restrict__ logit,
                     const float* __restrict__ g,
                     const float* __restrict__ b,
                     unsigned short* outp)
{
    const int token = blockIdx.x * 4 + (threadIdx.x >> 6);
    const int lane  = threadIdx.x & 63;
    const size_t base = (size_t)token * DCC + lane * 8;
    const int c0 = lane * 8;

    short8 zr = *(const short8*)(z + base);
    float zv[8], s = 0.f, q = 0.f;
    #pragma unroll
    for (int j = 0; j < 8; ++j) {
        zv[j] = bf2f((unsigned short)zr[j]);
        s += zv[j]; q += zv[j] * zv[j];
    }
    s = wave_reduce_sum(s); q = wave_reduce_sum(q);
    float m1 = s * (1.0f / DCC);
    float r1 = rsqrtf(q * (1.0f / DCC) - m1 * m1 + 1e-5f);

    float4 g0 = *(const float4*)(g + c0), g1 = *(const float4*)(g + c0 + 4);
    float4 b0 = *(const float4*)(b + c0), b1 = *(const float4*)(b + c0 + 4);
    float4 p0 = *(const float4*)(logit + c0), p1 = *(const float4*)(logit + c0 + 4);
    float gg[8] = {g0.x,g0.y,g0.z,g0.w,g1.x,g1.y,g1.z,g1.w};
    float bb[8] = {b0.x,b0.y,b0.z,b0.w,b1.x,b1.y,b1.z,b1.w};
    float pv[8] = {p0.x,p0.y,p0.z,p0.w,p1.x,p1.y,p1.z,p1.w};

    short8 ar = *(const short8*)(a + base);
    short8 tr = *(const short8*)(t + base);
    short8 lr = *(const short8*)(lat + base);

    float tv[8], s2 = 0.f, q2 = 0.f;
    #pragma unroll
    for (int j = 0; j < 8; ++j) {
        float comp = (zv[j] - m1) * r1 * gg[j] + bb[j];
        float prec = 1.0f / (1.0f + __expf(-pv[j]));
        float val  = bf2f((unsigned short)ar[j])
                   + 0.5f * (comp - bf2f((unsigned short)tr[j])) * prec
                   + 0.1f * bf2f((unsigned short)lr[j]);
        tv[j] = val;
        s2 += val; q2 += val * val;
    }
    s2 = wave_reduce_sum(s2); q2 = wave_reduce_sum(q2);
    float m2 = s2 * (1.0f / DCC);
    float r2 = rsqrtf(q2 * (1.0f / DCC) - m2 * m2 + 1e-5f);

    short8 o;
    #pragma unroll
    for (int j = 0; j < 8; ++j)
        o[j] = (short)f2bf((tv[j] - m2) * r2 * gg[j] + bb[j]);
    *(short8*)(outp + base) = o;
}

// ---------------------------------------------------------------------------
extern "C" void kernel_launch(void* const* d_in, const int* in_sizes, int n_in,
                              void* d_out, int out_size, void* d_ws, size_t ws_size,
                              hipStream_t stream)
{
    const float* qwen   = (const float*)d_in[0];
    const float* obs    = (const float*)d_in[1];
    const float* proj_W = (const float*)d_in[2];
    const float* proj_b = (const float*)d_in[3];
    const float* fuse_W = (const float*)d_in[4];
    const float* fuse_b = (const float*)d_in[5];
    const float* up_W   = (const float*)d_in[6];
    const float* up_b   = (const float*)d_in[7];
    const float* lat_W  = (const float*)d_in[8];
    const float* lat_b  = (const float*)d_in[9];
    const float* plogit = (const float*)d_in[10];
    const float* ln_g   = (const float*)d_in[11];
    const float* ln_b   = (const float*)d_in[12];
    const float* down_W = (const float*)d_in[13];
    const float* down_b = (const float*)d_in[14];
    const float* out1_W = (const float*)d_in[15];
    const float* out1_b = (const float*)d_in[16];
    const float* out2_W = (const float*)d_in[17];
    const float* out2_b = (const float*)d_in[18];
    float* out = (float*)d_out;

    // ---- ws layout (ushort): cat | x0 | acts0..3 | weights  = 94.4 MB
    unsigned short* wsu = (unsigned short*)d_ws;
    unsigned short* catbuf = wsu;                          // 16,777,216
    unsigned short* x0b    = wsu + 16777216;               // 4,194,304
    unsigned short* acts16[4] = {
        wsu + 20971520, wsu + 20971520 + TOKH,
        wsu + 20971520 + 2 * TOKH, wsu + 20971520 + 3 * TOKH };
    unsigned short* w16    = wsu + 37748736;               // 9,437,184
    unsigned short* projW16 = w16;                         // 4,194,304
    unsigned short* fuseW16 = w16 + 4194304;               // 1,048,576
    unsigned short* upW16   = w16 + 5242880;               // 1,048,576
    unsigned short* latW16  = w16 + 6291456;               // 1,048,576
    unsigned short* downW16 = w16 + 7340032;               //   786,432
    unsigned short* out1W16 = w16 + 8126464;               //   262,144
    unsigned short* out2W16 = w16 + 8388608;               // 1,048,576
    unsigned short* h16     = catbuf;                      // alias (cat dead after fuse)

    // ---- d_out overlays (64 MiB, fully rewritten by final GEMM)
    unsigned short* outu = (unsigned short*)d_out;
    // phase A: two bf16 obs slices (2 x 33.5 MB = exactly d_out)
    // phase B: pred a/b, z, lat[0..3] (7 x 8.4 MB)
    unsigned short* pred16a = outu;
    unsigned short* pred16b = outu + TOKH;
    unsigned short* z16     = outu + 2 * TOKH;
    unsigned short* lat16[4] = { outu + 3*TOKH, outu + 4*TOKH, outu + 5*TOKH, outu + 6*TOKH };

    dim3 blk(256);
    dim3 lngrid(NTOK / 4);

    auto cvt = [&](const float* s, unsigned short* d, int n) {
        int n4 = n / 4;
        cvt_kernel<<<dim3((n4 + 255) / 256), blk, 0, stream>>>(s, d, n4);
    };
    // weight conversions (every launch; ws re-poisoned by harness)
    cvt(proj_W, projW16, 4 * DCC * DMD);
    cvt(fuse_W, fuseW16, DCC * 4 * DCC);
    cvt(up_W,   upW16,   4 * DCC * DCC);
    cvt(lat_W,  latW16,  4 * DCC * DCC);
    cvt(down_W, downW16, 3 * DCC * DCC);
    cvt(out1_W, out1W16, DCC * DCC);
    cvt(out2_W, out2W16, DMD * DCC);

    // ---- proj: obs -> bf16 pairwise into d_out, then z=2 GEMM into cat cols
    for (int p = 0; p < 2; ++p) {
        cvt(obs + (size_t)p * 2 * NTOK * DMD, outu, 2 * NTOK * DMD);
        GArgs a{};
        for (int q = 0; q < 2; ++q) {
            int o = 2 * p + q;
            a.A[q]    = outu + (size_t)q * NTOK * DMD;
            a.W[q]    = projW16 + (size_t)o * DCC * DMD;
            a.bias[q] = proj_b + o * DCC;
            a.C[q]    = catbuf + o * DCC;        // ldc = 2048, column offset
        }
        gemm16<false, false><<<dim3(DCC/128, NTOK/128, 2), blk, 0, stream>>>(
            a, DMD, DMD, 0, 4 * DCC, DMD);
    }
    // ---- fuse: x0 = cat @ fuse_W^T + fuse_b  (K=2048)
    {
        GArgs a{};
        a.A[0] = catbuf; a.W[0] = fuseW16; a.bias[0] = fuse_b; a.C[0] = x0b;
        gemm16<false, false><<<dim3(DCC/128, NTOK/128, 1), blk, 0, stream>>>(
            a, 4 * DCC, 4 * DCC, 0, DCC, 4 * DCC);
    }

    // ---- initial bottom-up pass
    for (int i = 0; i < 4; ++i) {
        GArgs a{};
        a.A[0] = (i == 0) ? x0b : acts16[i - 1];
        a.W[0] = upW16 + (size_t)i * DCC * DCC;
        a.bias[0] = up_b + i * DCC;
        a.C[0] = z16;
        gemm16<false, false><<<dim3(DCC/128, NTOK/128, 1), blk, 0, stream>>>(
            a, DCC, DCC, 0, DCC, DCC);
        ln16_kernel<<<lngrid, blk, 0, stream>>>(z16, ln_g + i * DCC, ln_b + i * DCC, acts16[i]);
    }

    // ---- settling iterations
    for (int s = 0; s < 5; ++s) {
        // batched independents: pred0, pred1, lat0..lat3 (all from pre-sweep acts)
        {
            GArgs a{};
            a.A[0] = acts16[1]; a.W[0] = downW16 + (size_t)1 * DCC * DCC;
            a.bias[0] = down_b + 1 * DCC; a.C[0] = pred16a;
            a.A[1] = acts16[2]; a.W[1] = downW16 + (size_t)2 * DCC * DCC;
            a.bias[1] = down_b + 2 * DCC; a.C[1] = pred16b;
            for (int i = 0; i < 4; ++i) {
                a.A[2 + i] = acts16[i];
                a.W[2 + i] = latW16 + (size_t)i * DCC * DCC;
                a.bias[2 + i] = lat_b + i * DCC;
                a.C[2 + i] = lat16[i];
            }
            gemm16<false, false><<<dim3(DCC/128, NTOK/128, 6), blk, 0, stream>>>(
                a, DCC, DCC, 0, DCC, DCC);
        }
        // sequential chain: up GEMM + fused update per layer
        for (int i = 0; i < 4; ++i) {
            GArgs a{};
            a.A[0] = (i == 0) ? x0b : acts16[i - 1];
            a.W[0] = upW16 + (size_t)i * DCC * DCC;
            a.bias[0] = up_b + i * DCC;
            a.C[0] = z16;
            gemm16<false, false><<<dim3(DCC/128, NTOK/128, 1), blk, 0, stream>>>(
                a, DCC, DCC, 0, DCC, DCC);
            const unsigned short* tgt = (i == 0) ? pred16a : (i == 1) ? pred16b : acts16[i];
            update16_kernel<<<lngrid, blk, 0, stream>>>(
                z16, acts16[i], tgt, lat16[i],
                plogit + i * DCC, ln_g + i * DCC, ln_b + i * DCC, acts16[i]);
        }
    }

    // ---- head
    {
        GArgs a{};
        a.A[0] = acts16[3]; a.W[0] = out1W16; a.bias[0] = out1_b; a.C[0] = h16;
        gemm16<false, true><<<dim3(DCC/128, NTOK/128, 1), blk, 0, stream>>>(
            a, DCC, DCC, 0, DCC, DCC);
    }
    {
        GArgs a{};
        a.A[0] = h16; a.W[0] = out2W16; a.bias[0] = out2_b;
        a.add[0] = qwen; a.C[0] = out;
        gemm16<true, false><<<dim3(DMD/128, NTOK/128, 1), blk, 0, stream>>>(
            a, DCC, DCC, DMD, DMD, DCC);
    }
}